// Round 1
// baseline (930.642 us; speedup 1.0000x reference)
//
#include <hip/hip_runtime.h>
#include <math.h>

// ---------------- problem constants ----------------
#define NB      8732          // number of default boxes
#define NCLS    81            // classes incl. background
#define NFG     80            // foreground classes
#define TOPK    200           // per-class NMS candidates
#define MAXOUT  20            // final detections
#define SCORE_MIN_F 0.05f
#define NMS_IOU_F   0.5f
#define CONF_TH_F   0.2f
#define OHW     300
#define IHW     4096
#define X_ELEMS (3*OHW*OHW)   // 270000
#define B_OFF   270000
#define L_OFF   270080
#define S_OFF   270100
#define V_OFF   270120

__device__ __constant__ int COCO[81] = {
  1,2,3,4,5,6,7,8,9,10,11,13,14,15,16,17,18,19,20,21,22,23,24,25,27,28,31,32,
  33,34,35,36,37,38,39,40,41,42,43,44,46,47,48,49,50,51,52,53,54,55,56,57,58,
  59,60,61,62,63,64,65,67,70,72,73,74,75,76,77,78,79,80,81,82,84,85,86,87,88,
  89,90,91};

// ---------------- kernel 1: normalize + bilinear resize (align_corners) ----
__global__ __launch_bounds__(256) void resize_kernel(const float* __restrict__ img,
                                                     float* __restrict__ out)
{
    int o = blockIdx.x * 256 + threadIdx.x;
    if (o >= X_ELEMS) return;
    int ox = o % OHW;
    int t  = o / OHW;
    int oy = t % OHW;
    int ch = t / OHW;

    const float r = (float)(4095.0 / 299.0);   // f32, matches jnp f32 scalar promote
    float sy = (float)oy * r;
    int y0 = (int)floorf(sy);
    y0 = min(max(y0, 0), IHW - 2);
    float wy = sy - (float)y0;
    float sx = (float)ox * r;
    int x0 = (int)floorf(sx);
    x0 = min(max(x0, 0), IHW - 2);
    float wx = sx - (float)x0;

    const float* p = img + (size_t)ch * IHW * IHW;
    size_t base0 = (size_t)y0 * IHW + x0;
    size_t base1 = base0 + IHW;
    float v00 = p[base0],     v01 = p[base0 + 1];
    float v10 = p[base1],     v11 = p[base1 + 1];
    // normalize-before-resize, applied per sample (identical f32 ops)
    v00 = (v00 * 255.0f - 128.0f) / 128.0f;
    v01 = (v01 * 255.0f - 128.0f) / 128.0f;
    v10 = (v10 * 255.0f - 128.0f) / 128.0f;
    v11 = (v11 * 255.0f - 128.0f) / 128.0f;

    float left  = v00 * (1.0f - wy) + v10 * wy;   // rows first (H), then cols (W)
    float right = v01 * (1.0f - wy) + v11 * wy;
    out[o] = left * (1.0f - wx) + right * wx;
}

// ---------------- kernel 2: decode boxes + softmax scores -----------------
__global__ __launch_bounds__(256) void decode_kernel(const float* __restrict__ ploc,
                                                     const float* __restrict__ plabel,
                                                     const float* __restrict__ dboxes,
                                                     float* __restrict__ ltrb,
                                                     float* __restrict__ scores_t)
{
    int i = blockIdx.x * 256 + threadIdx.x;
    if (i >= NB) return;

    float l0 = ploc[0 * NB + i];
    float l1 = ploc[1 * NB + i];
    float l2 = ploc[2 * NB + i];
    float l3 = ploc[3 * NB + i];
    float4 db = ((const float4*)dboxes)[i];   // x,y,w,h
    float x = (l0 * 0.1f) * db.z + db.x;
    float y = (l1 * 0.1f) * db.w + db.y;
    float w = expf(l2 * 0.2f) * db.z;
    float h = expf(l3 * 0.2f) * db.w;
    float4 bb;
    bb.x = x - 0.5f * w;
    bb.y = y - 0.5f * h;
    bb.z = x + 0.5f * w;
    bb.w = y + 0.5f * h;
    ((float4*)ltrb)[i] = bb;

    // softmax over 81 classes (column i of plabel [81, NB])
    float mx = -1e30f;
    for (int k = 0; k < NCLS; k++) mx = fmaxf(mx, plabel[k * NB + i]);
    float s = 0.0f;
    for (int k = 0; k < NCLS; k++) s += expf(plabel[k * NB + i] - mx);
    for (int c = 0; c < NFG; c++) {
        float e = expf(plabel[(c + 1) * NB + i] - mx);
        scores_t[c * NB + i] = e / s;
    }
}

// ---------------- block argmax helper (tie -> lower index) ----------------
__device__ __forceinline__ void bmax3(float& av, int& ai, int& ap,
                                      float v, int i, int p)
{
    if (v > av || (v == av && i < ai)) { av = v; ai = i; ap = p; }
}

// after return, *outv/*outi/*outp (shared) are valid for ALL threads
__device__ __forceinline__ void block_best(float bv, int bi, int bp,
                                           float* swv, int* swi, int* swp,
                                           volatile float* outv, volatile int* outi,
                                           volatile int* outp, int tid)
{
    for (int off = 32; off; off >>= 1) {
        float v2 = __shfl_down(bv, off, 64);
        int   i2 = __shfl_down(bi, off, 64);
        int   p2 = __shfl_down(bp, off, 64);
        bmax3(bv, bi, bp, v2, i2, p2);
    }
    int wid = tid >> 6;
    if ((tid & 63) == 0) { swv[wid] = bv; swi[wid] = bi; swp[wid] = bp; }
    __syncthreads();
    if (tid == 0) {
        float gv = swv[0]; int gi = swi[0]; int gp = swp[0];
        for (int w = 1; w < 4; w++) bmax3(gv, gi, gp, swv[w], swi[w], swp[w]);
        *outv = gv; *outi = gi; *outp = gp;
    }
    __syncthreads();
}

// ---------------- kernel 3: per-class top-200 + greedy NMS ----------------
#define NMS_CAP 6144

__global__ __launch_bounds__(256) void nms_kernel(const float* __restrict__ scores_t,
                                                  const float* __restrict__ ltrb,
                                                  float* __restrict__ cls_scores,
                                                  int* __restrict__ cls_bidx)
{
    const int c   = blockIdx.x;
    const int tid = threadIdx.x;

    __shared__ float sv[NMS_CAP];
    __shared__ int   sidx[NMS_CAP];
    __shared__ int   scount;
    __shared__ float cval[TOPK];
    __shared__ int   cbid[TOPK];
    __shared__ float4 cbox[TOPK];
    __shared__ int   keep[TOPK];
    __shared__ unsigned int taken[(NB + 31) / 32];
    __shared__ float swv[4];  __shared__ int swi[4];  __shared__ int swp[4];
    __shared__ float bestv;   __shared__ int besti;   __shared__ int bestp;
    __shared__ int   supflag;
    __shared__ int   Ksh;

    if (tid == 0) { scount = 0; Ksh = TOPK; }
    for (int w = tid; w < (NB + 31) / 32; w += 256) taken[w] = 0u;
    __syncthreads();

    const float* row = scores_t + (size_t)c * NB;
    for (int i = tid; i < NB; i += 256) {
        float v = row[i];
        if (v > SCORE_MIN_F) {
            int p = atomicAdd(&scount, 1);
            if (p < NMS_CAP) { sv[p] = v; sidx[p] = i; }
        }
    }
    __syncthreads();
    const int  M   = scount;
    const bool ovf = (M > NMS_CAP);

    // ---- selection: exact sorted top-K (K<=200) with tie -> lower box idx
    for (int k = 0; k < TOPK; k++) {
        float bv = -1e30f; int bi = 0x7fffffff; int bp = -1;
        if (!ovf) {
            for (int j = tid; j < M; j += 256)
                bmax3(bv, bi, bp, sv[j], sidx[j], j);
        } else {
            for (int j = tid; j < NB; j += 256) {
                if (taken[j >> 5] & (1u << (j & 31))) continue;
                bmax3(bv, bi, bp, row[j], j, j);
            }
        }
        block_best(bv, bi, bp, swv, swi, swp, &bestv, &besti, &bestp, tid);
        float gbv = bestv; int gbi = besti; int gbp = bestp;
        if (gbv <= SCORE_MIN_F) { if (tid == 0) Ksh = k; break; }
        if (tid == 0) {
            cval[k] = gbv;
            cbid[k] = gbi;
            cbox[k] = ((const float4*)ltrb)[gbi];
            if (!ovf) sv[gbp] = -1e30f;
            else      taken[gbi >> 5] |= (1u << (gbi & 31));
        }
        __syncthreads();
    }
    __syncthreads();
    const int K = Ksh;

    // ---- greedy NMS over the K sorted candidates
    for (int i = 0; i < K; i++) {
        if (tid == 0) supflag = 0;
        __syncthreads();
        if (tid < i && keep[tid]) {
            float4 a = cbox[i];
            float4 b = cbox[tid];
            float lx = fmaxf(a.x, b.x), ly = fmaxf(a.y, b.y);
            float rx = fminf(a.z, b.z), ry = fminf(a.w, b.w);
            float w = fmaxf(rx - lx, 0.0f), h = fmaxf(ry - ly, 0.0f);
            float inter = w * h;
            float areaA = (a.z - a.x) * (a.w - a.y);
            float areaB = (b.z - b.x) * (b.w - b.y);
            float iou = inter / (areaA + areaB - inter);
            if (iou > NMS_IOU_F) supflag = 1;
        }
        __syncthreads();
        if (tid == 0) keep[i] = (cval[i] > SCORE_MIN_F) && !supflag;
        __syncthreads();
    }

    if (tid < TOPK) {
        int g = c * TOPK + tid;
        bool kept = (tid < K) && (keep[tid] != 0);
        cls_scores[g] = kept ? cval[tid] : 0.0f;
        cls_bidx[g]   = (tid < K) ? cbid[tid] : 0;
    }
}

// ---------------- kernel 4: global top-20 + final outputs -----------------
#define TK_CAP 2048
#define NFLAT  (NFG * TOPK)   // 16000

__global__ __launch_bounds__(256) void topk_kernel(const float* __restrict__ cls_scores,
                                                   const int* __restrict__ cls_bidx,
                                                   const float* __restrict__ ltrb,
                                                   float* __restrict__ out)
{
    const int tid = threadIdx.x;
    __shared__ float sv[TK_CAP];
    __shared__ int   sfi[TK_CAP];
    __shared__ int   scount;
    __shared__ unsigned int taken[(NFLAT + 31) / 32];
    __shared__ float swv[4];  __shared__ int swi[4];  __shared__ int swp[4];
    __shared__ float bestv;   __shared__ int besti;   __shared__ int bestp;

    if (tid == 0) scount = 0;
    for (int w = tid; w < (NFLAT + 31) / 32; w += 256) taken[w] = 0u;
    __syncthreads();

    for (int i = tid; i < NFLAT; i += 256) {
        float v = cls_scores[i];
        if (v > CONF_TH_F) {
            int p = atomicAdd(&scount, 1);
            if (p < TK_CAP) { sv[p] = v; sfi[p] = i; }
        }
    }
    __syncthreads();
    const int  M   = scount;
    const bool ovf = (M > TK_CAP);

    for (int k = 0; k < MAXOUT; k++) {
        float bv = -1e30f; int bi = 0x7fffffff; int bp = -1;
        if (!ovf) {
            for (int j = tid; j < M; j += 256)
                bmax3(bv, bi, bp, sv[j], sfi[j], j);
        } else {
            for (int j = tid; j < NFLAT; j += 256) {
                if (taken[j >> 5] & (1u << (j & 31))) continue;
                bmax3(bv, bi, bp, cls_scores[j], j, j);
            }
        }
        block_best(bv, bi, bp, swv, swi, swp, &bestv, &besti, &bestp, tid);
        float gbv = bestv; int gbi = besti; int gbp = bestp;
        if (tid == 0) {
            if (gbv > CONF_TH_F) {
                int cc   = gbi / TOPK;
                int orig = cls_bidx[gbi];
                float4 b = ((const float4*)ltrb)[orig];
                out[B_OFF + 4 * k + 0] = fminf(fmaxf(b.x, 0.0f), 1.0f) * 4096.0f;
                out[B_OFF + 4 * k + 1] = fminf(fmaxf(b.y, 0.0f), 1.0f) * 4096.0f;
                out[B_OFF + 4 * k + 2] = fminf(fmaxf(b.z, 0.0f), 1.0f) * 4096.0f;
                out[B_OFF + 4 * k + 3] = fminf(fmaxf(b.w, 0.0f), 1.0f) * 4096.0f;
                out[L_OFF + k] = (float)COCO[cc];
                out[S_OFF + k] = gbv;
                out[V_OFF + k] = 1.0f;
                if (!ovf) sv[gbp] = -1e30f;
                else      taken[gbi >> 5] |= (1u << (gbi & 31));
            } else {
                out[B_OFF + 4 * k + 0] = 0.0f;
                out[B_OFF + 4 * k + 1] = 0.0f;
                out[B_OFF + 4 * k + 2] = 0.0f;
                out[B_OFF + 4 * k + 3] = 0.0f;
                out[L_OFF + k] = 0.0f;
                out[S_OFF + k] = 0.0f;
                out[V_OFF + k] = 0.0f;
            }
        }
        __syncthreads();
    }
}

// ---------------- launch ---------------------------------------------------
extern "C" void kernel_launch(void* const* d_in, const int* in_sizes, int n_in,
                              void* d_out, int out_size, void* d_ws, size_t ws_size,
                              hipStream_t stream)
{
    const float* image  = (const float*)d_in[0];
    const float* ploc   = (const float*)d_in[1];
    const float* plabel = (const float*)d_in[2];
    const float* dboxes = (const float*)d_in[3];
    float* out = (float*)d_out;

    float* ws        = (float*)d_ws;
    float* ltrb      = ws;                         // 8732*4 floats
    float* scores_t  = ws + NB * 4;                // 80*8732 floats
    float* cls_scores= scores_t + (size_t)NFG * NB;// 16000 floats
    int*   cls_bidx  = (int*)(cls_scores + NFLAT); // 16000 ints

    resize_kernel<<<(X_ELEMS + 255) / 256, 256, 0, stream>>>(image, out);
    decode_kernel<<<(NB + 255) / 256, 256, 0, stream>>>(ploc, plabel, dboxes,
                                                        ltrb, scores_t);
    nms_kernel<<<NFG, 256, 0, stream>>>(scores_t, ltrb, cls_scores, cls_bidx);
    topk_kernel<<<1, 256, 0, stream>>>(cls_scores, cls_bidx, ltrb, out);
}

// Round 2
// 654.613 us; speedup vs baseline: 1.4217x; 1.4217x over previous
//
#include <hip/hip_runtime.h>
#include <math.h>

// ---------------- problem constants ----------------
#define NB      8732          // number of default boxes
#define NCLS    81            // classes incl. background
#define NFG     80            // foreground classes
#define TOPK    200           // per-class NMS candidates
#define MAXOUT  20            // final detections
#define SCORE_MIN_F 0.05f
#define NMS_IOU_F   0.5f
#define CONF_TH_F   0.2f
#define OHW     300
#define IHW     4096
#define X_ELEMS (3*OHW*OHW)   // 270000
#define B_OFF   270000
#define L_OFF   270080
#define S_OFF   270100
#define V_OFF   270120

__device__ __constant__ int COCO[81] = {
  1,2,3,4,5,6,7,8,9,10,11,13,14,15,16,17,18,19,20,21,22,23,24,25,27,28,31,32,
  33,34,35,36,37,38,39,40,41,42,43,44,46,47,48,49,50,51,52,53,54,55,56,57,58,
  59,60,61,62,63,64,65,67,70,72,73,74,75,76,77,78,79,80,81,82,84,85,86,87,88,
  89,90,91};

// ---------------- kernel 1: normalize + bilinear resize (align_corners) ----
__global__ __launch_bounds__(256) void resize_kernel(const float* __restrict__ img,
                                                     float* __restrict__ out)
{
    int o = blockIdx.x * 256 + threadIdx.x;
    if (o >= X_ELEMS) return;
    int ox = o % OHW;
    int t  = o / OHW;
    int oy = t % OHW;
    int ch = t / OHW;

    const float r = (float)(4095.0 / 299.0);   // f32, matches jnp f32 scalar promote
    float sy = (float)oy * r;
    int y0 = (int)floorf(sy);
    y0 = min(max(y0, 0), IHW - 2);
    float wy = sy - (float)y0;
    float sx = (float)ox * r;
    int x0 = (int)floorf(sx);
    x0 = min(max(x0, 0), IHW - 2);
    float wx = sx - (float)x0;

    const float* p = img + (size_t)ch * IHW * IHW;
    size_t base0 = (size_t)y0 * IHW + x0;
    size_t base1 = base0 + IHW;
    float v00 = p[base0],     v01 = p[base0 + 1];
    float v10 = p[base1],     v11 = p[base1 + 1];
    v00 = (v00 * 255.0f - 128.0f) / 128.0f;
    v01 = (v01 * 255.0f - 128.0f) / 128.0f;
    v10 = (v10 * 255.0f - 128.0f) / 128.0f;
    v11 = (v11 * 255.0f - 128.0f) / 128.0f;

    float left  = v00 * (1.0f - wy) + v10 * wy;   // rows first (H), then cols (W)
    float right = v01 * (1.0f - wy) + v11 * wy;
    out[o] = left * (1.0f - wx) + right * wx;
}

// ---------------- kernel 2: decode boxes + softmax scores -----------------
__global__ __launch_bounds__(256) void decode_kernel(const float* __restrict__ ploc,
                                                     const float* __restrict__ plabel,
                                                     const float* __restrict__ dboxes,
                                                     float* __restrict__ ltrb,
                                                     float* __restrict__ scores_t)
{
    int i = blockIdx.x * 256 + threadIdx.x;
    if (i >= NB) return;

    float l0 = ploc[0 * NB + i];
    float l1 = ploc[1 * NB + i];
    float l2 = ploc[2 * NB + i];
    float l3 = ploc[3 * NB + i];
    float4 db = ((const float4*)dboxes)[i];   // x,y,w,h
    float x = (l0 * 0.1f) * db.z + db.x;
    float y = (l1 * 0.1f) * db.w + db.y;
    float w = expf(l2 * 0.2f) * db.z;
    float h = expf(l3 * 0.2f) * db.w;
    float4 bb;
    bb.x = x - 0.5f * w;
    bb.y = y - 0.5f * h;
    bb.z = x + 0.5f * w;
    bb.w = y + 0.5f * h;
    ((float4*)ltrb)[i] = bb;

    // softmax over 81 classes (column i of plabel [81, NB])
    float mx = -1e30f;
    for (int k = 0; k < NCLS; k++) mx = fmaxf(mx, plabel[k * NB + i]);
    float s = 0.0f;
    for (int k = 0; k < NCLS; k++) s += expf(plabel[k * NB + i] - mx);
    for (int c = 0; c < NFG; c++) {
        float e = expf(plabel[(c + 1) * NB + i] - mx);
        scores_t[c * NB + i] = e / s;
    }
}

// ---------------- block argmax helper (tie -> lower index) ----------------
__device__ __forceinline__ void bmax3(float& av, int& ai, int& ap,
                                      float v, int i, int p)
{
    if (v > av || (v == av && i < ai)) { av = v; ai = i; ap = p; }
}

__device__ __forceinline__ void block_best(float bv, int bi, int bp,
                                           float* swv, int* swi, int* swp,
                                           volatile float* outv, volatile int* outi,
                                           volatile int* outp, int tid)
{
    for (int off = 32; off; off >>= 1) {
        float v2 = __shfl_down(bv, off, 64);
        int   i2 = __shfl_down(bi, off, 64);
        int   p2 = __shfl_down(bp, off, 64);
        bmax3(bv, bi, bp, v2, i2, p2);
    }
    int wid = tid >> 6;
    if ((tid & 63) == 0) { swv[wid] = bv; swi[wid] = bi; swp[wid] = bp; }
    __syncthreads();
    if (tid == 0) {
        float gv = swv[0]; int gi = swi[0]; int gp = swp[0];
        for (int w = 1; w < 4; w++) bmax3(gv, gi, gp, swv[w], swi[w], swp[w]);
        *outv = gv; *outi = gi; *outp = gp;
    }
    __syncthreads();
}

// ---------------- kernel 3: per-class top-200 + greedy NMS ----------------
// Sort path capacity (u64 keys). If exceeded (impossible-in-practice), falls
// back to exact 200x argmax over the global row with a taken-bitmap.
#define SORT_CAP 4096

__global__ __launch_bounds__(256) void nms_kernel(const float* __restrict__ scores_t,
                                                  const float* __restrict__ ltrb,
                                                  float* __restrict__ cls_scores,
                                                  int* __restrict__ cls_bidx)
{
    const int c   = blockIdx.x;
    const int tid = threadIdx.x;

    __shared__ unsigned long long skey[SORT_CAP];          // 32 KB
    __shared__ int   scount;
    __shared__ float cval[TOPK];
    __shared__ int   cbid[TOPK];
    __shared__ float4 cbox[TOPK];
    __shared__ unsigned long long supmat[TOPK * 4];        // 256-bit row per cand
    __shared__ unsigned long long keepw[4];
    __shared__ unsigned int taken[(NB + 31) / 32];
    __shared__ float swv[4];  __shared__ int swi[4];  __shared__ int swp[4];
    __shared__ float bestv;   __shared__ int besti;   __shared__ int bestp;
    __shared__ int   Ksh;

    if (tid == 0) { scount = 0; Ksh = TOPK; }
    __syncthreads();

    // ---- phase 1: compact candidates (score > 0.05) into LDS as sort keys
    const float* row = scores_t + (size_t)c * NB;
    for (int i = tid; i < NB; i += 256) {
        float v = row[i];
        if (v > SCORE_MIN_F) {
            int p = atomicAdd(&scount, 1);
            if (p < SORT_CAP)
                skey[p] = ((unsigned long long)__float_as_uint(v) << 32)
                        | (unsigned int)(~(unsigned int)i);
        }
    }
    __syncthreads();
    const int  M   = scount;
    const bool ovf = (M > SORT_CAP);
    int K;

    if (!ovf) {
        // ---- phase 2a: bitonic sort descending on u64 key (exact top-k order)
        int N = 256;
        while (N < M) N <<= 1;
        for (int i = M + tid; i < N; i += 256) skey[i] = 0ull;
        __syncthreads();
        for (int k2 = 2; k2 <= N; k2 <<= 1) {
            for (int j = k2 >> 1; j > 0; j >>= 1) {
                for (int i = tid; i < N; i += 256) {
                    int l = i ^ j;
                    if (l > i) {
                        unsigned long long a = skey[i], b = skey[l];
                        bool desc = ((i & k2) == 0);
                        if (desc ? (a < b) : (a > b)) { skey[i] = b; skey[l] = a; }
                    }
                }
                __syncthreads();
            }
        }
        K = (M < TOPK) ? M : TOPK;
        if (tid < K) {
            unsigned long long key = skey[tid];
            cval[tid] = __uint_as_float((unsigned int)(key >> 32));
            int bi = (int)(~(unsigned int)(key & 0xFFFFFFFFull));
            cbid[tid] = bi;
            cbox[tid] = ((const float4*)ltrb)[bi];
        }
        __syncthreads();
    } else {
        // ---- phase 2b: fallback — exact 200x argmax over global row
        for (int w = tid; w < (NB + 31) / 32; w += 256) taken[w] = 0u;
        __syncthreads();
        for (int k = 0; k < TOPK; k++) {
            float bv = -1e30f; int bi = 0x7fffffff; int bp = -1;
            for (int j = tid; j < NB; j += 256) {
                if (taken[j >> 5] & (1u << (j & 31))) continue;
                bmax3(bv, bi, bp, row[j], j, j);
            }
            block_best(bv, bi, bp, swv, swi, swp, &bestv, &besti, &bestp, tid);
            float gbv = bestv; int gbi = besti;
            if (gbv <= SCORE_MIN_F) { if (tid == 0) Ksh = k; __syncthreads(); break; }
            if (tid == 0) {
                cval[k] = gbv;
                cbid[k] = gbi;
                cbox[k] = ((const float4*)ltrb)[gbi];
                taken[gbi >> 5] |= (1u << (gbi & 31));
            }
            __syncthreads();
        }
        __syncthreads();
        K = Ksh;
    }

    // ---- phase 3: suppression bitmatrix — supmat[i] bit j = IOU(i,j)>0.5, j<i
    for (int t = tid; t < K * 4; t += 256) {
        int i = t >> 2;
        int w = t & 3;
        unsigned long long bits = 0ull;
        int jlo = w * 64;
        int jhi = (jlo + 64 < i) ? (jlo + 64) : i;
        if (jlo < i) {
            float4 a = cbox[i];
            float areaA = (a.z - a.x) * (a.w - a.y);
            for (int j = jlo; j < jhi; j++) {
                float4 b = cbox[j];
                float lx = fmaxf(a.x, b.x), ly = fmaxf(a.y, b.y);
                float rx = fminf(a.z, b.z), ry = fminf(a.w, b.w);
                float ww = fmaxf(rx - lx, 0.0f), hh = fmaxf(ry - ly, 0.0f);
                float inter = ww * hh;
                float areaB = (b.z - b.x) * (b.w - b.y);
                float iou = inter / (areaA + areaB - inter);
                if (iou > NMS_IOU_F) bits |= (1ull << (j - jlo));
            }
        }
        supmat[t] = bits;
    }
    __syncthreads();

    // ---- phase 4: sequential greedy scan (single thread, register bitmask)
    if (tid == 0) {
        unsigned long long k0 = 0, k1 = 0, k2 = 0, k3 = 0;
        for (int i = 0; i < K; i++) {
            const unsigned long long* r = &supmat[i * 4];
            unsigned long long s = (r[0] & k0) | (r[1] & k1) | (r[2] & k2) | (r[3] & k3);
            if (s == 0ull) {   // not suppressed -> keep (all cands have val>0.05)
                if      (i < 64)  k0 |= 1ull << i;
                else if (i < 128) k1 |= 1ull << (i - 64);
                else if (i < 192) k2 |= 1ull << (i - 128);
                else              k3 |= 1ull << (i - 192);
            }
        }
        keepw[0] = k0; keepw[1] = k1; keepw[2] = k2; keepw[3] = k3;
    }
    __syncthreads();

    // ---- phase 5: outputs
    if (tid < TOPK) {
        int g = c * TOPK + tid;
        bool kept = (tid < K) &&
                    ((keepw[tid >> 6] >> (tid & 63)) & 1ull);
        cls_scores[g] = kept ? cval[tid] : 0.0f;
        cls_bidx[g]   = (tid < K) ? cbid[tid] : 0;
    }
}

// ---------------- kernel 4: global top-20 + final outputs -----------------
#define TK_CAP 2048
#define NFLAT  (NFG * TOPK)   // 16000

__global__ __launch_bounds__(256) void topk_kernel(const float* __restrict__ cls_scores,
                                                   const int* __restrict__ cls_bidx,
                                                   const float* __restrict__ ltrb,
                                                   float* __restrict__ out)
{
    const int tid = threadIdx.x;
    __shared__ float sv[TK_CAP];
    __shared__ int   sfi[TK_CAP];
    __shared__ int   scount;
    __shared__ unsigned int taken[(NFLAT + 31) / 32];
    __shared__ float swv[4];  __shared__ int swi[4];  __shared__ int swp[4];
    __shared__ float bestv;   __shared__ int besti;   __shared__ int bestp;

    if (tid == 0) scount = 0;
    for (int w = tid; w < (NFLAT + 31) / 32; w += 256) taken[w] = 0u;
    __syncthreads();

    for (int i = tid; i < NFLAT; i += 256) {
        float v = cls_scores[i];
        if (v > CONF_TH_F) {
            int p = atomicAdd(&scount, 1);
            if (p < TK_CAP) { sv[p] = v; sfi[p] = i; }
        }
    }
    __syncthreads();
    const int  M   = scount;
    const bool ovf = (M > TK_CAP);

    for (int k = 0; k < MAXOUT; k++) {
        float bv = -1e30f; int bi = 0x7fffffff; int bp = -1;
        if (!ovf) {
            for (int j = tid; j < M; j += 256)
                bmax3(bv, bi, bp, sv[j], sfi[j], j);
        } else {
            for (int j = tid; j < NFLAT; j += 256) {
                if (taken[j >> 5] & (1u << (j & 31))) continue;
                bmax3(bv, bi, bp, cls_scores[j], j, j);
            }
        }
        block_best(bv, bi, bp, swv, swi, swp, &bestv, &besti, &bestp, tid);
        float gbv = bestv; int gbi = besti; int gbp = bestp;
        if (tid == 0) {
            if (gbv > CONF_TH_F) {
                int cc   = gbi / TOPK;
                int orig = cls_bidx[gbi];
                float4 b = ((const float4*)ltrb)[orig];
                out[B_OFF + 4 * k + 0] = fminf(fmaxf(b.x, 0.0f), 1.0f) * 4096.0f;
                out[B_OFF + 4 * k + 1] = fminf(fmaxf(b.y, 0.0f), 1.0f) * 4096.0f;
                out[B_OFF + 4 * k + 2] = fminf(fmaxf(b.z, 0.0f), 1.0f) * 4096.0f;
                out[B_OFF + 4 * k + 3] = fminf(fmaxf(b.w, 0.0f), 1.0f) * 4096.0f;
                out[L_OFF + k] = (float)COCO[cc];
                out[S_OFF + k] = gbv;
                out[V_OFF + k] = 1.0f;
                if (!ovf) sv[gbp] = -1e30f;
                else      taken[gbi >> 5] |= (1u << (gbi & 31));
            } else {
                out[B_OFF + 4 * k + 0] = 0.0f;
                out[B_OFF + 4 * k + 1] = 0.0f;
                out[B_OFF + 4 * k + 2] = 0.0f;
                out[B_OFF + 4 * k + 3] = 0.0f;
                out[L_OFF + k] = 0.0f;
                out[S_OFF + k] = 0.0f;
                out[V_OFF + k] = 0.0f;
            }
        }
        __syncthreads();
    }
}

// ---------------- launch ---------------------------------------------------
extern "C" void kernel_launch(void* const* d_in, const int* in_sizes, int n_in,
                              void* d_out, int out_size, void* d_ws, size_t ws_size,
                              hipStream_t stream)
{
    const float* image  = (const float*)d_in[0];
    const float* ploc   = (const float*)d_in[1];
    const float* plabel = (const float*)d_in[2];
    const float* dboxes = (const float*)d_in[3];
    float* out = (float*)d_out;

    float* ws        = (float*)d_ws;
    float* ltrb      = ws;                         // 8732*4 floats
    float* scores_t  = ws + NB * 4;                // 80*8732 floats
    float* cls_scores= scores_t + (size_t)NFG * NB;// 16000 floats
    int*   cls_bidx  = (int*)(cls_scores + NFLAT); // 16000 ints

    resize_kernel<<<(X_ELEMS + 255) / 256, 256, 0, stream>>>(image, out);
    decode_kernel<<<(NB + 255) / 256, 256, 0, stream>>>(ploc, plabel, dboxes,
                                                        ltrb, scores_t);
    nms_kernel<<<NFG, 256, 0, stream>>>(scores_t, ltrb, cls_scores, cls_bidx);
    topk_kernel<<<1, 256, 0, stream>>>(cls_scores, cls_bidx, ltrb, out);
}

// Round 3
// 478.239 us; speedup vs baseline: 1.9460x; 1.3688x over previous
//
#include <hip/hip_runtime.h>
#include <math.h>

// ---------------- problem constants ----------------
#define NB      8732          // number of default boxes
#define NCLS    81            // classes incl. background
#define NFG     80            // foreground classes
#define TOPK    200           // per-class NMS candidates
#define MAXOUT  20            // final detections
#define SCORE_MIN_F 0.05f
#define NMS_IOU_F   0.5f
#define CONF_TH_F   0.2f
#define OHW     300
#define IHW     4096
#define X_ELEMS (3*OHW*OHW)   // 270000
#define B_OFF   270000
#define L_OFF   270080
#define S_OFF   270100
#define V_OFF   270120
#define NFLAT   (NFG * TOPK)  // 16000

__device__ __constant__ int COCO[81] = {
  1,2,3,4,5,6,7,8,9,10,11,13,14,15,16,17,18,19,20,21,22,23,24,25,27,28,31,32,
  33,34,35,36,37,38,39,40,41,42,43,44,46,47,48,49,50,51,52,53,54,55,56,57,58,
  59,60,61,62,63,64,65,67,70,72,73,74,75,76,77,78,79,80,81,82,84,85,86,87,88,
  89,90,91};

// ---------------- kernel 1: normalize + bilinear resize (align_corners) ----
// One block per (channel, output-row): stage the two source rows into LDS
// with coalesced float4 loads, then compute 300 outputs from LDS.
__global__ __launch_bounds__(256) void resize_kernel(const float* __restrict__ img,
                                                     float* __restrict__ out)
{
    const int b   = blockIdx.x;       // 0..899
    const int tid = threadIdx.x;
    const int ch  = b / OHW;
    const int oy  = b % OHW;

    const float r = (float)(4095.0 / 299.0);   // f32, matches jnp f32 promote
    float sy = (float)oy * r;
    int y0 = (int)floorf(sy);
    y0 = min(max(y0, 0), IHW - 2);
    float wy = sy - (float)y0;

    __shared__ __align__(16) float r0s[IHW];
    __shared__ __align__(16) float r1s[IHW];

    const float* p0 = img + (size_t)ch * IHW * IHW + (size_t)y0 * IHW;
    const float* p1 = p0 + IHW;
    for (int i = tid; i < IHW / 4; i += 256) {
        float4 a = ((const float4*)p0)[i];
        float4 c = ((const float4*)p1)[i];
        a.x = (a.x * 255.0f - 128.0f) / 128.0f;
        a.y = (a.y * 255.0f - 128.0f) / 128.0f;
        a.z = (a.z * 255.0f - 128.0f) / 128.0f;
        a.w = (a.w * 255.0f - 128.0f) / 128.0f;
        c.x = (c.x * 255.0f - 128.0f) / 128.0f;
        c.y = (c.y * 255.0f - 128.0f) / 128.0f;
        c.z = (c.z * 255.0f - 128.0f) / 128.0f;
        c.w = (c.w * 255.0f - 128.0f) / 128.0f;
        ((float4*)r0s)[i] = a;
        ((float4*)r1s)[i] = c;
    }
    __syncthreads();

    float* orow = out + (size_t)ch * OHW * OHW + (size_t)oy * OHW;
    for (int ox = tid; ox < OHW; ox += 256) {
        float sx = (float)ox * r;
        int x0 = (int)floorf(sx);
        x0 = min(max(x0, 0), IHW - 2);
        float wx = sx - (float)x0;
        float left  = r0s[x0]     * (1.0f - wy) + r1s[x0]     * wy;
        float right = r0s[x0 + 1] * (1.0f - wy) + r1s[x0 + 1] * wy;
        orow[ox] = left * (1.0f - wx) + right * wx;
    }
}

// ---------------- kernel 2: decode boxes + softmax scores -----------------
__global__ __launch_bounds__(256) void decode_kernel(const float* __restrict__ ploc,
                                                     const float* __restrict__ plabel,
                                                     const float* __restrict__ dboxes,
                                                     float* __restrict__ ltrb,
                                                     float* __restrict__ scores_t)
{
    int i = blockIdx.x * 256 + threadIdx.x;
    if (i >= NB) return;

    float l0 = ploc[0 * NB + i];
    float l1 = ploc[1 * NB + i];
    float l2 = ploc[2 * NB + i];
    float l3 = ploc[3 * NB + i];
    float4 db = ((const float4*)dboxes)[i];   // x,y,w,h
    float x = (l0 * 0.1f) * db.z + db.x;
    float y = (l1 * 0.1f) * db.w + db.y;
    float w = expf(l2 * 0.2f) * db.z;
    float h = expf(l3 * 0.2f) * db.w;
    float4 bb;
    bb.x = x - 0.5f * w;
    bb.y = y - 0.5f * h;
    bb.z = x + 0.5f * w;
    bb.w = y + 0.5f * h;
    ((float4*)ltrb)[i] = bb;

    // softmax over 81 classes (column i of plabel [81, NB])
    float mx = -1e30f;
    for (int k = 0; k < NCLS; k++) mx = fmaxf(mx, plabel[k * NB + i]);
    float s = 0.0f;
    for (int k = 0; k < NCLS; k++) s += expf(plabel[k * NB + i] - mx);
    for (int c = 0; c < NFG; c++) {
        float e = expf(plabel[(c + 1) * NB + i] - mx);
        scores_t[c * NB + i] = e / s;
    }
}

// ---------------- block argmax helper (tie -> lower index) ----------------
__device__ __forceinline__ void bmax3(float& av, int& ai, int& ap,
                                      float v, int i, int p)
{
    if (v > av || (v == av && i < ai)) { av = v; ai = i; ap = p; }
}

__device__ __forceinline__ void block_best(float bv, int bi, int bp,
                                           float* swv, int* swi, int* swp,
                                           volatile float* outv, volatile int* outi,
                                           volatile int* outp, int tid)
{
    for (int off = 32; off; off >>= 1) {
        float v2 = __shfl_down(bv, off, 64);
        int   i2 = __shfl_down(bi, off, 64);
        int   p2 = __shfl_down(bp, off, 64);
        bmax3(bv, bi, bp, v2, i2, p2);
    }
    int wid = tid >> 6;
    if ((tid & 63) == 0) { swv[wid] = bv; swi[wid] = bi; swp[wid] = bp; }
    __syncthreads();
    if (tid == 0) {
        float gv = swv[0]; int gi = swi[0]; int gp = swp[0];
        for (int w = 1; w < 4; w++) bmax3(gv, gi, gp, swv[w], swi[w], swp[w]);
        *outv = gv; *outi = gi; *outp = gp;
    }
    __syncthreads();
}

// ---------------- kernel 3: per-class top-200 + greedy NMS ----------------
// Sort path capacity (u64 keys). If exceeded, falls back to exact 200x argmax
// over the global row with a taken-bitmap.
#define SORT_CAP 4096

__global__ __launch_bounds__(256) void nms_kernel(const float* __restrict__ scores_t,
                                                  const float* __restrict__ ltrb,
                                                  float* __restrict__ cls_scores,
                                                  int* __restrict__ cls_bidx)
{
    const int c   = blockIdx.x;
    const int tid = threadIdx.x;

    __shared__ unsigned long long skey[SORT_CAP];          // 32 KB
    __shared__ int   scount;
    __shared__ float cval[TOPK];
    __shared__ int   cbid[TOPK];
    __shared__ float4 cbox[TOPK];
    __shared__ unsigned long long supmat[TOPK * 4];        // 256-bit row per cand
    __shared__ unsigned long long keepw[4];
    __shared__ unsigned int taken[(NB + 31) / 32];
    __shared__ float swv[4];  __shared__ int swi[4];  __shared__ int swp[4];
    __shared__ float bestv;   __shared__ int besti;   __shared__ int bestp;
    __shared__ int   Ksh;

    if (tid == 0) { scount = 0; Ksh = TOPK; }
    __syncthreads();

    // ---- phase 1: compact candidates (score > 0.05) into LDS as sort keys
    const float* row = scores_t + (size_t)c * NB;
    for (int i = tid; i < NB; i += 256) {
        float v = row[i];
        if (v > SCORE_MIN_F) {
            int p = atomicAdd(&scount, 1);
            if (p < SORT_CAP)
                skey[p] = ((unsigned long long)__float_as_uint(v) << 32)
                        | (unsigned int)(~(unsigned int)i);
        }
    }
    __syncthreads();
    const int  M   = scount;
    const bool ovf = (M > SORT_CAP);
    int K;

    if (!ovf) {
        // ---- phase 2a: bitonic sort descending on u64 key (exact top-k order)
        int N = 256;
        while (N < M) N <<= 1;
        for (int i = M + tid; i < N; i += 256) skey[i] = 0ull;
        __syncthreads();
        for (int k2 = 2; k2 <= N; k2 <<= 1) {
            for (int j = k2 >> 1; j > 0; j >>= 1) {
                for (int i = tid; i < N; i += 256) {
                    int l = i ^ j;
                    if (l > i) {
                        unsigned long long a = skey[i], b = skey[l];
                        bool desc = ((i & k2) == 0);
                        if (desc ? (a < b) : (a > b)) { skey[i] = b; skey[l] = a; }
                    }
                }
                __syncthreads();
            }
        }
        K = (M < TOPK) ? M : TOPK;
        if (tid < K) {
            unsigned long long key = skey[tid];
            cval[tid] = __uint_as_float((unsigned int)(key >> 32));
            int bi = (int)(~(unsigned int)(key & 0xFFFFFFFFull));
            cbid[tid] = bi;
            cbox[tid] = ((const float4*)ltrb)[bi];
        }
        __syncthreads();
    } else {
        // ---- phase 2b: fallback — exact 200x argmax over global row
        for (int w = tid; w < (NB + 31) / 32; w += 256) taken[w] = 0u;
        __syncthreads();
        for (int k = 0; k < TOPK; k++) {
            float bv = -1e30f; int bi = 0x7fffffff; int bp = -1;
            for (int j = tid; j < NB; j += 256) {
                if (taken[j >> 5] & (1u << (j & 31))) continue;
                bmax3(bv, bi, bp, row[j], j, j);
            }
            block_best(bv, bi, bp, swv, swi, swp, &bestv, &besti, &bestp, tid);
            float gbv = bestv; int gbi = besti;
            if (gbv <= SCORE_MIN_F) { if (tid == 0) Ksh = k; __syncthreads(); break; }
            if (tid == 0) {
                cval[k] = gbv;
                cbid[k] = gbi;
                cbox[k] = ((const float4*)ltrb)[gbi];
                taken[gbi >> 5] |= (1u << (gbi & 31));
            }
            __syncthreads();
        }
        __syncthreads();
        K = Ksh;
    }

    // ---- phase 3: suppression bitmatrix — supmat[i] bit j = IOU(i,j)>0.5, j<i
    for (int t = tid; t < K * 4; t += 256) {
        int i = t >> 2;
        int w = t & 3;
        unsigned long long bits = 0ull;
        int jlo = w * 64;
        int jhi = (jlo + 64 < i) ? (jlo + 64) : i;
        if (jlo < i) {
            float4 a = cbox[i];
            float areaA = (a.z - a.x) * (a.w - a.y);
            for (int j = jlo; j < jhi; j++) {
                float4 b = cbox[j];
                float lx = fmaxf(a.x, b.x), ly = fmaxf(a.y, b.y);
                float rx = fminf(a.z, b.z), ry = fminf(a.w, b.w);
                float ww = fmaxf(rx - lx, 0.0f), hh = fmaxf(ry - ly, 0.0f);
                float inter = ww * hh;
                float areaB = (b.z - b.x) * (b.w - b.y);
                float iou = inter / (areaA + areaB - inter);
                if (iou > NMS_IOU_F) bits |= (1ull << (j - jlo));
            }
        }
        supmat[t] = bits;
    }
    __syncthreads();

    // ---- phase 4: sequential greedy scan (single thread, register bitmask)
    if (tid == 0) {
        unsigned long long k0 = 0, k1 = 0, k2 = 0, k3 = 0;
        for (int i = 0; i < K; i++) {
            const unsigned long long* rr = &supmat[i * 4];
            unsigned long long s = (rr[0] & k0) | (rr[1] & k1) | (rr[2] & k2) | (rr[3] & k3);
            if (s == 0ull) {
                if      (i < 64)  k0 |= 1ull << i;
                else if (i < 128) k1 |= 1ull << (i - 64);
                else if (i < 192) k2 |= 1ull << (i - 128);
                else              k3 |= 1ull << (i - 192);
            }
        }
        keepw[0] = k0; keepw[1] = k1; keepw[2] = k2; keepw[3] = k3;
    }
    __syncthreads();

    // ---- phase 5: outputs
    if (tid < TOPK) {
        int g = c * TOPK + tid;
        bool kept = (tid < K) &&
                    ((keepw[tid >> 6] >> (tid & 63)) & 1ull);
        cls_scores[g] = kept ? cval[tid] : 0.0f;
        cls_bidx[g]   = (tid < K) ? cbid[tid] : 0;
    }
}

// ---------------- kernel 4: global top-20 + final outputs -----------------
// All 16000 scores staged in LDS; 20 exact argmax passes (remove-by-index,
// lax.top_k tie semantics); parallel epilogue for the dependent index->box
// load chain.
__global__ __launch_bounds__(256) void topk_kernel(const float* __restrict__ cls_scores,
                                                   const int* __restrict__ cls_bidx,
                                                   const float* __restrict__ ltrb,
                                                   float* __restrict__ out)
{
    const int tid = threadIdx.x;
    __shared__ float sv[NFLAT];                  // 62.5 KB
    __shared__ float swv[4];  __shared__ int swi[4];  __shared__ int swp[4];
    __shared__ float bestv;   __shared__ int besti;   __shared__ int bestp;
    __shared__ float selv[MAXOUT];
    __shared__ int   seli[MAXOUT];

    for (int i = tid; i < NFLAT; i += 256) sv[i] = cls_scores[i];
    __syncthreads();

    for (int k = 0; k < MAXOUT; k++) {
        float bv = -1e30f; int bi = 0x7fffffff;
        for (int j = tid; j < NFLAT; j += 256) {
            float v = sv[j];
            if (v > bv || (v == bv && j < bi)) { bv = v; bi = j; }
        }
        block_best(bv, bi, bi, swv, swi, swp, &bestv, &besti, &bestp, tid);
        if (tid == 0) {
            selv[k] = bestv;
            seli[k] = besti;
            sv[besti] = -1e30f;   // remove; exact top-k (16000 >= 20 always)
        }
        __syncthreads();
    }

    if (tid < MAXOUT) {
        float v  = selv[tid];
        int   fi = seli[tid];
        bool  val = v > CONF_TH_F;
        int   cc  = fi / TOPK;
        int   orig = cls_bidx[fi];                  // 20 concurrent loads
        float4 bx = ((const float4*)ltrb)[orig];    // one dependent round
        float b0 = fminf(fmaxf(bx.x, 0.0f), 1.0f) * 4096.0f;
        float b1 = fminf(fmaxf(bx.y, 0.0f), 1.0f) * 4096.0f;
        float b2 = fminf(fmaxf(bx.z, 0.0f), 1.0f) * 4096.0f;
        float b3 = fminf(fmaxf(bx.w, 0.0f), 1.0f) * 4096.0f;
        out[B_OFF + 4 * tid + 0] = val ? b0 : 0.0f;
        out[B_OFF + 4 * tid + 1] = val ? b1 : 0.0f;
        out[B_OFF + 4 * tid + 2] = val ? b2 : 0.0f;
        out[B_OFF + 4 * tid + 3] = val ? b3 : 0.0f;
        out[L_OFF + tid] = val ? (float)COCO[cc] : 0.0f;
        out[S_OFF + tid] = val ? v : 0.0f;
        out[V_OFF + tid] = val ? 1.0f : 0.0f;
    }
}

// ---------------- launch ---------------------------------------------------
extern "C" void kernel_launch(void* const* d_in, const int* in_sizes, int n_in,
                              void* d_out, int out_size, void* d_ws, size_t ws_size,
                              hipStream_t stream)
{
    const float* image  = (const float*)d_in[0];
    const float* ploc   = (const float*)d_in[1];
    const float* plabel = (const float*)d_in[2];
    const float* dboxes = (const float*)d_in[3];
    float* out = (float*)d_out;

    float* ws        = (float*)d_ws;
    float* ltrb      = ws;                         // 8732*4 floats
    float* scores_t  = ws + NB * 4;                // 80*8732 floats
    float* cls_scores= scores_t + (size_t)NFG * NB;// 16000 floats
    int*   cls_bidx  = (int*)(cls_scores + NFLAT); // 16000 ints

    resize_kernel<<<3 * OHW, 256, 0, stream>>>(image, out);
    decode_kernel<<<(NB + 255) / 256, 256, 0, stream>>>(ploc, plabel, dboxes,
                                                        ltrb, scores_t);
    nms_kernel<<<NFG, 256, 0, stream>>>(scores_t, ltrb, cls_scores, cls_bidx);
    topk_kernel<<<1, 256, 0, stream>>>(cls_scores, cls_bidx, ltrb, out);
}